// Round 7
// baseline (467.133 us; speedup 1.0000x reference)
//
#include <hip/hip_runtime.h>
#include <hip/hip_bf16.h>
#include <stdint.h>

// RWKV4 time-mix for B=4, T=2048, H=2048 on gfx950.
#define B_ 4
#define T_ 2048
#define H_ 2048
#define BT_ (B_ * T_)
#define BH_ (B_ * H_)
#define CH_ 32              // number of time chunks for the WKV scan
#define CL_ (T_ / CH_)      // chunk length = 64
#define NKT_ (H_ / 64)      // 32 K-tiles of BK=64 for the GEMM

typedef __bf16 bf16x8 __attribute__((ext_vector_type(8)));
typedef float f32x4 __attribute__((ext_vector_type(4)));

// async global->LDS, 16B per lane. LDS dest is wave-uniform base + lane*16.
__device__ inline void async16(const void* g, void* l) {
  __builtin_amdgcn_global_load_lds(
      (__attribute__((address_space(1))) uint32_t*)(void*)(uintptr_t)g,
      (__attribute__((address_space(3))) uint32_t*)l,
      16, 0, 0);
}

// ---------------------------------------------------------------- f32 -> bf16
__global__ __launch_bounds__(256) void cvt_bf16_kernel(
    const float* __restrict__ src, __bf16* __restrict__ dst) {
  int i = (blockIdx.x * 256 + threadIdx.x) * 8;
  const float4* s4 = (const float4*)(src + i);
  float4 a = s4[0], b = s4[1];
  bf16x8 o;
  o[0] = (__bf16)a.x; o[1] = (__bf16)a.y; o[2] = (__bf16)a.z; o[3] = (__bf16)a.w;
  o[4] = (__bf16)b.x; o[5] = (__bf16)b.y; o[6] = (__bf16)b.z; o[7] = (__bf16)b.w;
  *(bf16x8*)(dst + i) = o;
}

// ------------------------------------------------- LayerNorm + token-shift mix
__global__ __launch_bounds__(256) void ln_mix_kernel(
    const float* __restrict__ h, const float* __restrict__ lnw,
    const float* __restrict__ lnb, const float* __restrict__ mk,
    const float* __restrict__ mv, const float* __restrict__ mr,
    __bf16* __restrict__ xk, __bf16* __restrict__ xv, __bf16* __restrict__ xr,
    float* __restrict__ xlast) {
  const int row = blockIdx.x;          // b*T + t
  const int t = row & (T_ - 1);
  const int tid = threadIdx.x;
  const bool hasprev = (t != 0);

  const float4* cr = (const float4*)(h + (size_t)row * H_);
  float4 c0 = cr[tid * 2 + 0], c1 = cr[tid * 2 + 1];
  float4 p0 = {0.f, 0.f, 0.f, 0.f}, p1 = {0.f, 0.f, 0.f, 0.f};
  if (hasprev) {
    const float4* pr = (const float4*)(h + (size_t)(row - 1) * H_);
    p0 = pr[tid * 2 + 0]; p1 = pr[tid * 2 + 1];
  }
  float4 red;
  red.x = c0.x + c0.y + c0.z + c0.w + c1.x + c1.y + c1.z + c1.w;
  red.y = c0.x * c0.x + c0.y * c0.y + c0.z * c0.z + c0.w * c0.w +
          c1.x * c1.x + c1.y * c1.y + c1.z * c1.z + c1.w * c1.w;
  red.z = p0.x + p0.y + p0.z + p0.w + p1.x + p1.y + p1.z + p1.w;
  red.w = p0.x * p0.x + p0.y * p0.y + p0.z * p0.z + p0.w * p0.w +
          p1.x * p1.x + p1.y * p1.y + p1.z * p1.z + p1.w * p1.w;
  #pragma unroll
  for (int off = 32; off; off >>= 1) {
    red.x += __shfl_down(red.x, off);
    red.y += __shfl_down(red.y, off);
    red.z += __shfl_down(red.z, off);
    red.w += __shfl_down(red.w, off);
  }
  __shared__ float4 rbuf[4];
  const int lane = tid & 63, wid = tid >> 6;
  if (lane == 0) rbuf[wid] = red;
  __syncthreads();
  float4 tot;
  tot.x = rbuf[0].x + rbuf[1].x + rbuf[2].x + rbuf[3].x;
  tot.y = rbuf[0].y + rbuf[1].y + rbuf[2].y + rbuf[3].y;
  tot.z = rbuf[0].z + rbuf[1].z + rbuf[2].z + rbuf[3].z;
  tot.w = rbuf[0].w + rbuf[1].w + rbuf[2].w + rbuf[3].w;

  const float inv = 1.0f / (float)H_;
  float mu = tot.x * inv;
  float rstd = rsqrtf(fmaxf(tot.y * inv - mu * mu, 0.f) + 1e-5f);
  float mup = tot.z * inv;
  float rstdp = rsqrtf(fmaxf(tot.w * inv - mup * mup, 0.f) + 1e-5f);

  float xc[8] = {c0.x, c0.y, c0.z, c0.w, c1.x, c1.y, c1.z, c1.w};
  float xp[8] = {p0.x, p0.y, p0.z, p0.w, p1.x, p1.y, p1.z, p1.w};
  const float4* W4 = (const float4*)lnw;
  const float4* Bv4 = (const float4*)lnb;
  const float4* MK4 = (const float4*)mk;
  const float4* MV4 = (const float4*)mv;
  const float4* MR4 = (const float4*)mr;
  float4 w0 = W4[tid * 2], w1 = W4[tid * 2 + 1];
  float4 b0 = Bv4[tid * 2], b1 = Bv4[tid * 2 + 1];
  float4 k0 = MK4[tid * 2], k1 = MK4[tid * 2 + 1];
  float4 v0 = MV4[tid * 2], v1 = MV4[tid * 2 + 1];
  float4 r0 = MR4[tid * 2], r1 = MR4[tid * 2 + 1];
  float wa[8] = {w0.x, w0.y, w0.z, w0.w, w1.x, w1.y, w1.z, w1.w};
  float ba[8] = {b0.x, b0.y, b0.z, b0.w, b1.x, b1.y, b1.z, b1.w};
  float ka[8] = {k0.x, k0.y, k0.z, k0.w, k1.x, k1.y, k1.z, k1.w};
  float va[8] = {v0.x, v0.y, v0.z, v0.w, v1.x, v1.y, v1.z, v1.w};
  float ra[8] = {r0.x, r0.y, r0.z, r0.w, r1.x, r1.y, r1.z, r1.w};

  bf16x8 ok_, ov_, or_;
  float xls[8];
  #pragma unroll
  for (int e = 0; e < 8; e++) {
    float x = (xc[e] - mu) * rstd * wa[e] + ba[e];
    float sx = hasprev ? (xp[e] - mup) * rstdp * wa[e] + ba[e] : 0.f;
    ok_[e] = (__bf16)(sx + ka[e] * (x - sx));
    ov_[e] = (__bf16)(sx + va[e] * (x - sx));
    or_[e] = (__bf16)(sx + ra[e] * (x - sx));
    xls[e] = x;
  }
  size_t obase = (size_t)row * H_ + tid * 8;
  *(bf16x8*)(xk + obase) = ok_;
  *(bf16x8*)(xv + obase) = ov_;
  *(bf16x8*)(xr + obase) = or_;
  if (t == T_ - 1) {
    float* dst = xlast + (size_t)(row >> 11) * H_ + tid * 8;
    #pragma unroll
    for (int e = 0; e < 8; e++) dst[e] = xls[e];
  }
}

// ----------------------- bf16 NT GEMM, 256^2 tile, BK=64, swizzled LDS
// R6 geometry/addressing (verified), NEW: asymmetric rings enabling COUNTED
// vmcnt (T4, m218 +38%): A ring x2 (64 KB) + B ring x3 (96 KB) = 160 KB LDS.
// Per tile kt: issue A(kt+1)->slotA[(kt+1)&1] then B(kt+2)->slotB[(kt+2)%3]
// (8 loads/thread, A first), compute, then s_waitcnt vmcnt(4): drains A(kt+1)
// and all older (incl. B(kt+1)), keeps B(kt+2) in flight across the barrier.
// Loads never drain to 0 in the main loop.  setprio around MFMA (T5), no
// sched_barrier pinning (m141).
// Race-freedom: A(kt+1) overwrites A(kt-1) (reads consumed before end-of-kt-1
// barrier); B(kt+2) overwrites B(kt-1) (read at kt-1 phase 0).
// MODE 0: store f32. MODE 1: sigmoid -> bf16. MODE 2: residual add -> f32.
template <int MODE>
__global__ __launch_bounds__(512, 1) void gemm_nt5(
    const __bf16* __restrict__ A, const __bf16* __restrict__ Bw,
    float* __restrict__ outf, __bf16* __restrict__ outb,
    const float* __restrict__ resid) {
  __shared__ __align__(16) char ldsA[2][32768];
  __shared__ __align__(16) char ldsB[3][32768];

  // bijective XCD swizzle: 256 blocks, 8 XCDs, chunks of 32 (4 bm-rows x 8 bn)
  const int wgid = blockIdx.x;
  const int lin = (wgid & 7) * 32 + (wgid >> 3);
  const int bm = lin >> 3;          // 0..31  (M/256)
  const int bn = lin & 7;           // 0..7   (N/256)

  const int tid = threadIdx.x;
  const int lane = tid & 63, wv = tid >> 6;
  const int wm = wv >> 2;           // 0..1
  const int wn = wv & 3;            // 0..3
  const int rr = lane & 15, q = lane >> 4;

  f32x4 acc[8][4];
  #pragma unroll
  for (int m = 0; m < 8; m++)
    #pragma unroll
    for (int n = 0; n < 4; n++) acc[m][n] = (f32x4){0.f, 0.f, 0.f, 0.f};

  const char* Ag = (const char*)A + (size_t)(bm * 256) * (H_ * 2);
  const char* Bg = (const char*)Bw + (size_t)(bn * 256) * (H_ * 2);

  // stage addressing: round = 64 rows x 128 B; lane l covers row wv*8+(l>>3),
  // 16-B col (l&7), fetching global col (l&7)^(l>>3)  (inverse swizzle).
  const int srow = wv * 8 + (lane >> 3);
  const int scol = ((lane & 7) ^ (lane >> 3)) << 4;

  // ds_read swizzle: row&7 == rr&7 for all fragment reads.
  const int rsw = rr & 7;

#define STAGE_M(Mg_, dstb_, kt_)                                                \
  {                                                                             \
    _Pragma("unroll")                                                           \
    for (int hh_ = 0; hh_ < 2; hh_++) {                                         \
      _Pragma("unroll")                                                         \
      for (int rd_ = 0; rd_ < 2; rd_++) {                                       \
        char* dst_ = (dstb_) + hh_ * 16384 + rd_ * 8192 + wv * 1024;            \
        const char* src_ = (Mg_) + (size_t)(hh_ * 128 + rd_ * 64 + srow) * (H_ * 2) \
                           + (kt_) * 128 + scol;                                \
        async16(src_, dst_);                                                    \
      }                                                                         \
    }                                                                           \
  }

  // prologue: A(0), B(0), B(1); keep B(1) in flight.
  STAGE_M(Ag, ldsA[0], 0);
  STAGE_M(Bg, ldsB[0], 0);
  STAGE_M(Bg, ldsB[1], 1);
  asm volatile("s_waitcnt vmcnt(4)" ::: "memory");
  __builtin_amdgcn_s_barrier();

  for (int kt = 0; kt < NKT_; kt++) {
    const char* Alds = ldsA[kt & 1];
    const char* Blds = ldsB[kt % 3];

    // issue next stages first (A before B: vmcnt(4) keeps only B(kt+2))
    if (kt + 1 < NKT_) STAGE_M(Ag, ldsA[(kt + 1) & 1], kt + 1);
    if (kt + 2 < NKT_) STAGE_M(Bg, ldsB[(kt + 2) % 3], kt + 2);

    // B-fragments: read once per tile, held in regs across quadrants
    bf16x8 bfr[4][2];
    #pragma unroll
    for (int ni = 0; ni < 4; ni++)
      #pragma unroll
      for (int ks = 0; ks < 2; ks++) {
        int row_t = wn * 64 + ni * 16 + rr;
        bfr[ni][ks] = *(const bf16x8*)(Blds + row_t * 128 +
                                       (((ks * 4 + q) ^ rsw) << 4));
      }

    __builtin_amdgcn_s_setprio(1);
    #pragma unroll
    for (int p = 0; p < 4; p++) {
      bf16x8 af[2][2];
      #pragma unroll
      for (int mi = 0; mi < 2; mi++)
        #pragma unroll
        for (int ks = 0; ks < 2; ks++) {
          int row_t = wm * 128 + p * 32 + mi * 16 + rr;
          af[mi][ks] = *(const bf16x8*)(Alds + row_t * 128 +
                                        (((ks * 4 + q) ^ rsw) << 4));
        }
      #pragma unroll
      for (int ks = 0; ks < 2; ks++)
        #pragma unroll
        for (int mi = 0; mi < 2; mi++)
          #pragma unroll
          for (int ni = 0; ni < 4; ni++)
            acc[p * 2 + mi][ni] = __builtin_amdgcn_mfma_f32_16x16x32_bf16(
                af[mi][ks], bfr[ni][ks], acc[p * 2 + mi][ni], 0, 0, 0);
    }
    __builtin_amdgcn_s_setprio(0);

    // counted tile-boundary sync: A(kt+1) + B(kt+1) drained, B(kt+2) flying.
    if (kt + 1 < NKT_) {
      if (kt + 2 < NKT_) {
        asm volatile("s_waitcnt vmcnt(4)" ::: "memory");
      } else {
        asm volatile("s_waitcnt vmcnt(0)" ::: "memory");
      }
      __builtin_amdgcn_s_barrier();
    }
  }
#undef STAGE_M

  // epilogue: acc[m][n] row = bm*256 + wm*128 + m*16 + q*4 + rg, col = bn*256
  // + wn*64 + n*16 + rr.
  const int r0 = bm * 256 + wm * 128 + q * 4;
  const int c0 = bn * 256 + wn * 64 + rr;
  #pragma unroll
  for (int m = 0; m < 8; m++) {
    #pragma unroll
    for (int n = 0; n < 4; n++) {
      int col = c0 + n * 16;
      #pragma unroll
      for (int rg = 0; rg < 4; rg++) {
        int rowg = r0 + m * 16 + rg;
        size_t idx = (size_t)rowg * H_ + col;
        float vv = acc[m][n][rg];
        if (MODE == 0) {
          outf[idx] = vv;
        } else if (MODE == 1) {
          outb[idx] = (__bf16)(1.f / (1.f + __expf(-vv)));
        } else {
          outf[idx] = resid[idx] + vv;
        }
      }
    }
  }
}

// ------------------------------------------------- WKV chunked scan (3 passes)
__global__ __launch_bounds__(256) void wkv_pass1(
    const float* __restrict__ k, const float* __restrict__ v,
    const float* __restrict__ td,
    float* __restrict__ cs_num, float* __restrict__ cs_den,
    float* __restrict__ cs_norm) {
  const int id = blockIdx.x * 256 + threadIdx.x;  // 0..B*H-1
  const int c = blockIdx.y;                       // chunk
  const int b = id >> 11;
  const int hh = id & (H_ - 1);
  const float decay = -__expf(td[hh]);
  float num = 0.f, den = 0.f, norm = -INFINITY;

  const int UN = 16;
  for (int t0 = c * CL_; t0 < (c + 1) * CL_; t0 += UN) {
    float kk[UN], vv[UN];
    size_t base = ((size_t)b * T_ + t0) * H_ + hh;
    #pragma unroll
    for (int i = 0; i < UN; i++) {
      kk[i] = k[base + (size_t)i * H_];
      vv[i] = v[base + (size_t)i * H_];
    }
    #pragma unroll
    for (int i = 0; i < UN; i++) {
      float dpn = decay + norm;
      float nn = fmaxf(dpn, kk[i]);
      float ed = __expf(dpn - nn), ek = __expf(kk[i] - nn);
      num = ed * num + ek * vv[i];
      den = ed * den + ek;
      norm = nn;
    }
  }
  cs_num[c * BH_ + id] = num;
  cs_den[c * BH_ + id] = den;
  cs_norm[c * BH_ + id] = norm;
}

__global__ __launch_bounds__(256) void wkv_scan(
    const float* __restrict__ cs_num, const float* __restrict__ cs_den,
    const float* __restrict__ cs_norm, const float* __restrict__ td,
    float* __restrict__ px_num, float* __restrict__ px_den,
    float* __restrict__ px_norm) {
  const int id = blockIdx.x * 256 + threadIdx.x;  // 0..B*H-1
  const int hh = id & (H_ - 1);
  const float Lw = -__expf(td[hh]) * (float)CL_;  // CL_ * decay
  float num = 0.f, den = 0.f, norm = -INFINITY;
  for (int c = 0; c < CH_; c++) {
    px_num[c * BH_ + id] = num;
    px_den[c * BH_ + id] = den;
    px_norm[c * BH_ + id] = norm;
    float n_c = cs_num[c * BH_ + id];
    float d_c = cs_den[c * BH_ + id];
    float m_c = cs_norm[c * BH_ + id];
    float sn = norm + Lw;                 // shifted incoming norm
    float on = fmaxf(sn, m_c);            // m_c is always finite
    float ea = __expf(sn - on), eb = __expf(m_c - on);
    num = ea * num + eb * n_c;
    den = ea * den + eb * d_c;
    norm = on;
  }
}

__global__ __launch_bounds__(256) void wkv_pass2(
    const float* __restrict__ k, const float* __restrict__ v,
    const __bf16* __restrict__ r, const float* __restrict__ td,
    const float* __restrict__ cw,
    const float* __restrict__ px_num, const float* __restrict__ px_den,
    const float* __restrict__ px_norm,
    __bf16* __restrict__ a, float* __restrict__ ndn) {
  const int id = blockIdx.x * 256 + threadIdx.x;  // 0..B*H-1
  const int c = blockIdx.y;
  const int b = id >> 11;
  const int hh = id & (H_ - 1);
  const float decay = -__expf(td[hh]);
  const float cwv = cw[hh];
  float num = px_num[c * BH_ + id];
  float den = px_den[c * BH_ + id];
  float norm = px_norm[c * BH_ + id];

  const int UN = 16;
  for (int t0 = c * CL_; t0 < (c + 1) * CL_; t0 += UN) {
    float kk[UN], vv[UN], rrv[UN];
    size_t base = ((size_t)b * T_ + t0) * H_ + hh;
    #pragma unroll
    for (int i = 0; i < UN; i++) {
      kk[i] = k[base + (size_t)i * H_];
      vv[i] = v[base + (size_t)i * H_];
      rrv[i] = (float)r[base + (size_t)i * H_];
    }
    #pragma unroll
    for (int i = 0; i < UN; i++) {
      float kt = kk[i], vt = vv[i];
      float ct = cwv + kt;
      float cn = fmaxf(ct, norm);
      float ep = __expf(norm - cn), ec = __expf(ct - cn);
      float o = (ep * num + ec * vt) / (ep * den + ec);
      a[base + (size_t)i * H_] = (__bf16)(rrv[i] * o);
      float dpn = decay + norm;
      float nn = fmaxf(dpn, kt);
      float ed = __expf(dpn - nn), ek = __expf(kt - nn);
      num = ed * num + ek * vt;
      den = ed * den + ek;
      norm = nn;
    }
  }
  if (c == CH_ - 1) {
    ndn[id] = num;
    ndn[BH_ + id] = den;
    ndn[2 * BH_ + id] = norm;
  }
}

// ----------------------------------------------------------------------- host
extern "C" void kernel_launch(void* const* d_in, const int* in_sizes, int n_in,
                              void* d_out, int out_size, void* d_ws, size_t ws_size,
                              hipStream_t stream) {
  const float* h   = (const float*)d_in[0];
  const float* lnw = (const float*)d_in[1];
  const float* lnb = (const float*)d_in[2];
  const float* Wk  = (const float*)d_in[3];
  const float* Wv  = (const float*)d_in[4];
  const float* Wr  = (const float*)d_in[5];
  const float* Wo  = (const float*)d_in[6];
  const float* mk  = (const float*)d_in[7];
  const float* mv  = (const float*)d_in[8];
  const float* mr  = (const float*)d_in[9];
  const float* td  = (const float*)d_in[10];
  const float* cw  = (const float*)d_in[11];

  char* ws = (char*)d_ws;
  const size_t MB = 1048576;
  // 256 MB workspace layout:
  //   [0,32)    xk   (bf16, later reused as 'a' = r*wkv)
  //   [32,64)   xv   (bf16, later reused as 'r')
  //   [64,96)   xr   (bf16; dead after r-GEMM -> scan state lives here)
  //   [96,160)  kbuf (f32)
  //   [160,224) vbuf (f32)
  //   [224,256) Wk16/Wv16/Wr16/Wo16 (bf16, 8 MB each)
  __bf16* xk   = (__bf16*)(ws);
  __bf16* xv   = (__bf16*)(ws + 32 * MB);
  __bf16* xr   = (__bf16*)(ws + 64 * MB);
  float*  kbuf = (float*)(ws + 96 * MB);
  float*  vbuf = (float*)(ws + 160 * MB);
  __bf16* Wk16 = (__bf16*)(ws + 224 * MB);
  __bf16* Wv16 = Wk16 + (size_t)H_ * H_;
  __bf16* Wr16 = Wv16 + (size_t)H_ * H_;
  __bf16* Wo16 = Wr16 + (size_t)H_ * H_;
  float* cs_num  = (float*)(ws + 64 * MB);
  float* cs_den  = cs_num + (size_t)CH_ * BH_;
  float* cs_norm = cs_den + (size_t)CH_ * BH_;
  float* px_num  = cs_norm + (size_t)CH_ * BH_;
  float* px_den  = px_num + (size_t)CH_ * BH_;
  float* px_norm = px_den + (size_t)CH_ * BH_;

  float* out  = (float*)d_out;
  float* xlast = out + (size_t)BT_ * H_;
  float* ndn   = xlast + (size_t)B_ * H_;

  const int cvt_blocks = (H_ * H_) / (256 * 8);
  cvt_bf16_kernel<<<cvt_blocks, 256, 0, stream>>>(Wk, Wk16);
  cvt_bf16_kernel<<<cvt_blocks, 256, 0, stream>>>(Wv, Wv16);
  cvt_bf16_kernel<<<cvt_blocks, 256, 0, stream>>>(Wr, Wr16);
  cvt_bf16_kernel<<<cvt_blocks, 256, 0, stream>>>(Wo, Wo16);

  ln_mix_kernel<<<BT_, 256, 0, stream>>>(h, lnw, lnb, mk, mv, mr, xk, xv, xr, xlast);

  const int gemm_blocks = (BT_ / 256) * (H_ / 256);  // 32 * 8 = 256
  gemm_nt5<0><<<gemm_blocks, 512, 0, stream>>>(xk, Wk16, kbuf, nullptr, nullptr);
  gemm_nt5<0><<<gemm_blocks, 512, 0, stream>>>(xv, Wv16, vbuf, nullptr, nullptr);
  gemm_nt5<1><<<gemm_blocks, 512, 0, stream>>>(xr, Wr16, nullptr, xv /* r reuses xv */, nullptr);

  dim3 wg(BH_ / 256, CH_);
  wkv_pass1<<<wg, 256, 0, stream>>>(kbuf, vbuf, td, cs_num, cs_den, cs_norm);
  wkv_scan<<<BH_ / 256, 256, 0, stream>>>(cs_num, cs_den, cs_norm, td,
                                          px_num, px_den, px_norm);
  wkv_pass2<<<wg, 256, 0, stream>>>(kbuf, vbuf, xv, td, cw,
                                    px_num, px_den, px_norm,
                                    xk /* a reuses xk */, ndn);

  gemm_nt5<2><<<gemm_blocks, 512, 0, stream>>>(xk, Wo16, out, nullptr, h);
}

// Round 8
// 362.924 us; speedup vs baseline: 1.2871x; 1.2871x over previous
//
#include <hip/hip_runtime.h>
#include <hip/hip_bf16.h>
#include <stdint.h>

// RWKV4 time-mix for B=4, T=2048, H=2048 on gfx950.
#define B_ 4
#define T_ 2048
#define H_ 2048
#define BT_ (B_ * T_)
#define BH_ (B_ * H_)
#define CH_ 32              // number of time chunks for the WKV scan
#define CL_ (T_ / CH_)      // chunk length = 64
#define NKT_ (H_ / 64)      // 32 K-tiles of BK=64 for the GEMM

typedef __bf16 bf16x8 __attribute__((ext_vector_type(8)));
typedef float f32x4 __attribute__((ext_vector_type(4)));

// async global->LDS, 16B per lane. LDS dest is wave-uniform base + lane*16.
__device__ inline void async16(const void* g, void* l) {
  __builtin_amdgcn_global_load_lds(
      (__attribute__((address_space(1))) uint32_t*)(void*)(uintptr_t)g,
      (__attribute__((address_space(3))) uint32_t*)l,
      16, 0, 0);
}

// ------------------------------------------- f32 -> bf16 (all 4 weights, 1 launch)
__global__ __launch_bounds__(256) void cvt_bf16_kernel(
    const float* __restrict__ w0, const float* __restrict__ w1,
    const float* __restrict__ w2, const float* __restrict__ w3,
    __bf16* __restrict__ dst /* 4 contiguous H*H blocks */) {
  const float* srcs[4] = {w0, w1, w2, w3};
  const float* src = srcs[blockIdx.y];
  __bf16* d = dst + (size_t)blockIdx.y * H_ * H_;
  int i = (blockIdx.x * 256 + threadIdx.x) * 8;
  const float4* s4 = (const float4*)(src + i);
  float4 a = s4[0], b = s4[1];
  bf16x8 o;
  o[0] = (__bf16)a.x; o[1] = (__bf16)a.y; o[2] = (__bf16)a.z; o[3] = (__bf16)a.w;
  o[4] = (__bf16)b.x; o[5] = (__bf16)b.y; o[6] = (__bf16)b.z; o[7] = (__bf16)b.w;
  *(bf16x8*)(d + i) = o;
}

// ------------------------------------------------- LayerNorm + token-shift mix
__global__ __launch_bounds__(256) void ln_mix_kernel(
    const float* __restrict__ h, const float* __restrict__ lnw,
    const float* __restrict__ lnb, const float* __restrict__ mk,
    const float* __restrict__ mv, const float* __restrict__ mr,
    __bf16* __restrict__ xk, __bf16* __restrict__ xv, __bf16* __restrict__ xr,
    float* __restrict__ xlast) {
  const int row = blockIdx.x;          // b*T + t
  const int t = row & (T_ - 1);
  const int tid = threadIdx.x;
  const bool hasprev = (t != 0);

  const float4* cr = (const float4*)(h + (size_t)row * H_);
  float4 c0 = cr[tid * 2 + 0], c1 = cr[tid * 2 + 1];
  float4 p0 = {0.f, 0.f, 0.f, 0.f}, p1 = {0.f, 0.f, 0.f, 0.f};
  if (hasprev) {
    const float4* pr = (const float4*)(h + (size_t)(row - 1) * H_);
    p0 = pr[tid * 2 + 0]; p1 = pr[tid * 2 + 1];
  }
  float4 red;
  red.x = c0.x + c0.y + c0.z + c0.w + c1.x + c1.y + c1.z + c1.w;
  red.y = c0.x * c0.x + c0.y * c0.y + c0.z * c0.z + c0.w * c0.w +
          c1.x * c1.x + c1.y * c1.y + c1.z * c1.z + c1.w * c1.w;
  red.z = p0.x + p0.y + p0.z + p0.w + p1.x + p1.y + p1.z + p1.w;
  red.w = p0.x * p0.x + p0.y * p0.y + p0.z * p0.z + p0.w * p0.w +
          p1.x * p1.x + p1.y * p1.y + p1.z * p1.z + p1.w * p1.w;
  #pragma unroll
  for (int off = 32; off; off >>= 1) {
    red.x += __shfl_down(red.x, off);
    red.y += __shfl_down(red.y, off);
    red.z += __shfl_down(red.z, off);
    red.w += __shfl_down(red.w, off);
  }
  __shared__ float4 rbuf[4];
  const int lane = tid & 63, wid = tid >> 6;
  if (lane == 0) rbuf[wid] = red;
  __syncthreads();
  float4 tot;
  tot.x = rbuf[0].x + rbuf[1].x + rbuf[2].x + rbuf[3].x;
  tot.y = rbuf[0].y + rbuf[1].y + rbuf[2].y + rbuf[3].y;
  tot.z = rbuf[0].z + rbuf[1].z + rbuf[2].z + rbuf[3].z;
  tot.w = rbuf[0].w + rbuf[1].w + rbuf[2].w + rbuf[3].w;

  const float inv = 1.0f / (float)H_;
  float mu = tot.x * inv;
  float rstd = rsqrtf(fmaxf(tot.y * inv - mu * mu, 0.f) + 1e-5f);
  float mup = tot.z * inv;
  float rstdp = rsqrtf(fmaxf(tot.w * inv - mup * mup, 0.f) + 1e-5f);

  float xc[8] = {c0.x, c0.y, c0.z, c0.w, c1.x, c1.y, c1.z, c1.w};
  float xp[8] = {p0.x, p0.y, p0.z, p0.w, p1.x, p1.y, p1.z, p1.w};
  const float4* W4 = (const float4*)lnw;
  const float4* Bv4 = (const float4*)lnb;
  const float4* MK4 = (const float4*)mk;
  const float4* MV4 = (const float4*)mv;
  const float4* MR4 = (const float4*)mr;
  float4 w0 = W4[tid * 2], w1 = W4[tid * 2 + 1];
  float4 b0 = Bv4[tid * 2], b1 = Bv4[tid * 2 + 1];
  float4 k0 = MK4[tid * 2], k1 = MK4[tid * 2 + 1];
  float4 v0 = MV4[tid * 2], v1 = MV4[tid * 2 + 1];
  float4 r0 = MR4[tid * 2], r1 = MR4[tid * 2 + 1];
  float wa[8] = {w0.x, w0.y, w0.z, w0.w, w1.x, w1.y, w1.z, w1.w};
  float ba[8] = {b0.x, b0.y, b0.z, b0.w, b1.x, b1.y, b1.z, b1.w};
  float ka[8] = {k0.x, k0.y, k0.z, k0.w, k1.x, k1.y, k1.z, k1.w};
  float va[8] = {v0.x, v0.y, v0.z, v0.w, v1.x, v1.y, v1.z, v1.w};
  float ra[8] = {r0.x, r0.y, r0.z, r0.w, r1.x, r1.y, r1.z, r1.w};

  bf16x8 ok_, ov_, or_;
  float xls[8];
  #pragma unroll
  for (int e = 0; e < 8; e++) {
    float x = (xc[e] - mu) * rstd * wa[e] + ba[e];
    float sx = hasprev ? (xp[e] - mup) * rstdp * wa[e] + ba[e] : 0.f;
    ok_[e] = (__bf16)(sx + ka[e] * (x - sx));
    ov_[e] = (__bf16)(sx + va[e] * (x - sx));
    or_[e] = (__bf16)(sx + ra[e] * (x - sx));
    xls[e] = x;
  }
  size_t obase = (size_t)row * H_ + tid * 8;
  *(bf16x8*)(xk + obase) = ok_;
  *(bf16x8*)(xv + obase) = ov_;
  *(bf16x8*)(xr + obase) = or_;
  if (t == T_ - 1) {
    float* dst = xlast + (size_t)(row >> 11) * H_ + tid * 8;
    #pragma unroll
    for (int e = 0; e < 8; e++) dst[e] = xls[e];
  }
}

// ----------------------- bf16 NT GEMM, 256^2 tile, BK=64, swizzled LDS
// R6 schedule (best measured: 79 us, ~870 TF): per K-tile {issue 8 stage
// loads for kt+1 -> ds_read frags -> 64 MFMA -> vmcnt(0) -> s_barrier}.
// No sched_barrier pinning (m141), compiler free-schedules lgkmcnt.
// MODE 0: store bf16. MODE 1: sigmoid -> bf16. MODE 2: residual add -> f32.
template <int MODE>
__global__ __launch_bounds__(512, 1) void gemm_nt4(
    const __bf16* __restrict__ A, const __bf16* __restrict__ Bw,
    float* __restrict__ outf, __bf16* __restrict__ outb,
    const float* __restrict__ resid) {
  __shared__ __align__(16) char ring[2][65536];   // [buf][A 32K | B 32K]

  // bijective XCD swizzle: 256 blocks, 8 XCDs, chunks of 32 (4 bm-rows x 8 bn)
  const int wgid = blockIdx.x;
  const int lin = (wgid & 7) * 32 + (wgid >> 3);
  const int bm = lin >> 3;          // 0..31  (M/256)
  const int bn = lin & 7;           // 0..7   (N/256)

  const int tid = threadIdx.x;
  const int lane = tid & 63, wv = tid >> 6;
  const int wm = wv >> 2;           // 0..1
  const int wn = wv & 3;            // 0..3
  const int rr = lane & 15, q = lane >> 4;

  f32x4 acc[8][4];
  #pragma unroll
  for (int m = 0; m < 8; m++)
    #pragma unroll
    for (int n = 0; n < 4; n++) acc[m][n] = (f32x4){0.f, 0.f, 0.f, 0.f};

  const char* Ag = (const char*)A + (size_t)(bm * 256) * (H_ * 2);
  const char* Bg = (const char*)Bw + (size_t)(bn * 256) * (H_ * 2);

  // stage addressing: round = 64 rows x 128 B; lane l covers row wv*8+(l>>3),
  // 16-B col (l&7), fetching global col (l&7)^(l>>3)  (inverse swizzle).
  const int srow = wv * 8 + (lane >> 3);
  const int scol = ((lane & 7) ^ (lane >> 3)) << 4;

  // ds_read swizzle: row&7 == rr&7 for all fragment reads.
  const int rsw = rr & 7;

#define STAGE_TILE(kt_, buf_)                                                   \
  {                                                                             \
    char* base_ = ring[buf_];                                                   \
    _Pragma("unroll")                                                           \
    for (int mh_ = 0; mh_ < 2; mh_++) {                                         \
      const char* Mg_ = mh_ ? Bg : Ag;                                          \
      _Pragma("unroll")                                                         \
      for (int hh_ = 0; hh_ < 2; hh_++) {                                       \
        _Pragma("unroll")                                                       \
        for (int rd_ = 0; rd_ < 2; rd_++) {                                     \
          char* dst_ = base_ + mh_ * 32768 + hh_ * 16384 + rd_ * 8192 + wv * 1024; \
          const char* src_ = Mg_ + (size_t)(hh_ * 128 + rd_ * 64 + srow) * (H_ * 2) \
                             + (kt_) * 128 + scol;                              \
          async16(src_, dst_);                                                  \
        }                                                                       \
      }                                                                         \
    }                                                                           \
  }

  // prologue: stage tile 0, drain, barrier.
  STAGE_TILE(0, 0);
  asm volatile("s_waitcnt vmcnt(0)" ::: "memory");
  __builtin_amdgcn_s_barrier();

  for (int kt = 0; kt < NKT_; kt++) {
    const int cur = kt & 1, nxt = cur ^ 1;
    const char* Alds = ring[cur];
    const char* Blds = ring[cur] + 32768;

    // issue next tile's stages first (max slack: ~1 full tile before use)
    if (kt + 1 < NKT_) STAGE_TILE(kt + 1, nxt);

    // B-fragments: read once per tile, held in regs across quadrants
    bf16x8 bfr[4][2];
    #pragma unroll
    for (int ni = 0; ni < 4; ni++)
      #pragma unroll
      for (int ks = 0; ks < 2; ks++) {
        int row_t = wn * 64 + ni * 16 + rr;
        bfr[ni][ks] = *(const bf16x8*)(Blds + row_t * 128 +
                                       (((ks * 4 + q) ^ rsw) << 4));
      }

    #pragma unroll
    for (int p = 0; p < 4; p++) {
      bf16x8 af[2][2];
      #pragma unroll
      for (int mi = 0; mi < 2; mi++)
        #pragma unroll
        for (int ks = 0; ks < 2; ks++) {
          int row_t = wm * 128 + p * 32 + mi * 16 + rr;
          af[mi][ks] = *(const bf16x8*)(Alds + row_t * 128 +
                                        (((ks * 4 + q) ^ rsw) << 4));
        }
      #pragma unroll
      for (int ks = 0; ks < 2; ks++)
        #pragma unroll
        for (int mi = 0; mi < 2; mi++)
          #pragma unroll
          for (int ni = 0; ni < 4; ni++)
            acc[p * 2 + mi][ni] = __builtin_amdgcn_mfma_f32_16x16x32_bf16(
                af[mi][ks], bfr[ni][ks], acc[p * 2 + mi][ni], 0, 0, 0);
    }

    // single tile-boundary sync: own stages published, buffers swappable.
    if (kt + 1 < NKT_) {
      asm volatile("s_waitcnt vmcnt(0)" ::: "memory");
      __builtin_amdgcn_s_barrier();
    }
  }
#undef STAGE_TILE

  // epilogue: acc[m][n] row = bm*256 + wm*128 + m*16 + q*4 + rg, col = bn*256
  // + wn*64 + n*16 + rr.
  const int r0 = bm * 256 + wm * 128 + q * 4;
  const int c0 = bn * 256 + wn * 64 + rr;
  #pragma unroll
  for (int m = 0; m < 8; m++) {
    #pragma unroll
    for (int n = 0; n < 4; n++) {
      int col = c0 + n * 16;
      #pragma unroll
      for (int rg = 0; rg < 4; rg++) {
        int rowg = r0 + m * 16 + rg;
        size_t idx = (size_t)rowg * H_ + col;
        float vv = acc[m][n][rg];
        if (MODE == 0) {
          outb[idx] = (__bf16)vv;
        } else if (MODE == 1) {
          outb[idx] = (__bf16)(1.f / (1.f + __expf(-vv)));
        } else {
          outf[idx] = resid[idx] + vv;
        }
      }
    }
  }
}

// ------------------------------------------------- WKV chunked scan (3 passes)
// k, v are bf16 now (halves HBM traffic; ~0.4% rel err, well within budget).
__global__ __launch_bounds__(256) void wkv_pass1(
    const __bf16* __restrict__ k, const __bf16* __restrict__ v,
    const float* __restrict__ td,
    float* __restrict__ cs_num, float* __restrict__ cs_den,
    float* __restrict__ cs_norm) {
  const int id = blockIdx.x * 256 + threadIdx.x;  // 0..B*H-1
  const int c = blockIdx.y;                       // chunk
  const int b = id >> 11;
  const int hh = id & (H_ - 1);
  const float decay = -__expf(td[hh]);
  float num = 0.f, den = 0.f, norm = -INFINITY;

  const int UN = 16;
  for (int t0 = c * CL_; t0 < (c + 1) * CL_; t0 += UN) {
    float kk[UN], vv[UN];
    size_t base = ((size_t)b * T_ + t0) * H_ + hh;
    #pragma unroll
    for (int i = 0; i < UN; i++) {
      kk[i] = (float)k[base + (size_t)i * H_];
      vv[i] = (float)v[base + (size_t)i * H_];
    }
    #pragma unroll
    for (int i = 0; i < UN; i++) {
      float dpn = decay + norm;
      float nn = fmaxf(dpn, kk[i]);
      float ed = __expf(dpn - nn), ek = __expf(kk[i] - nn);
      num = ed * num + ek * vv[i];
      den = ed * den + ek;
      norm = nn;
    }
  }
  cs_num[c * BH_ + id] = num;
  cs_den[c * BH_ + id] = den;
  cs_norm[c * BH_ + id] = norm;
}

__global__ __launch_bounds__(256) void wkv_scan(
    const float* __restrict__ cs_num, const float* __restrict__ cs_den,
    const float* __restrict__ cs_norm, const float* __restrict__ td,
    float* __restrict__ px_num, float* __restrict__ px_den,
    float* __restrict__ px_norm) {
  const int id = blockIdx.x * 256 + threadIdx.x;  // 0..B*H-1
  const int hh = id & (H_ - 1);
  const float Lw = -__expf(td[hh]) * (float)CL_;  // CL_ * decay
  float num = 0.f, den = 0.f, norm = -INFINITY;
  for (int c = 0; c < CH_; c++) {
    px_num[c * BH_ + id] = num;
    px_den[c * BH_ + id] = den;
    px_norm[c * BH_ + id] = norm;
    float n_c = cs_num[c * BH_ + id];
    float d_c = cs_den[c * BH_ + id];
    float m_c = cs_norm[c * BH_ + id];
    float sn = norm + Lw;                 // shifted incoming norm
    float on = fmaxf(sn, m_c);            // m_c is always finite
    float ea = __expf(sn - on), eb = __expf(m_c - on);
    num = ea * num + eb * n_c;
    den = ea * den + eb * d_c;
    norm = on;
  }
}

__global__ __launch_bounds__(256) void wkv_pass2(
    const __bf16* __restrict__ k, const __bf16* __restrict__ v,
    const __bf16* __restrict__ r, const float* __restrict__ td,
    const float* __restrict__ cw,
    const float* __restrict__ px_num, const float* __restrict__ px_den,
    const float* __restrict__ px_norm,
    __bf16* __restrict__ a, float* __restrict__ ndn) {
  const int id = blockIdx.x * 256 + threadIdx.x;  // 0..B*H-1
  const int c = blockIdx.y;
  const int b = id >> 11;
  const int hh = id & (H_ - 1);
  const float decay = -__expf(td[hh]);
  const float cwv = cw[hh];
  float num = px_num[c * BH_ + id];
  float den = px_den[c * BH_ + id];
  float norm = px_norm[c * BH_ + id];

  const int UN = 16;
  for (int t0 = c * CL_; t0 < (c + 1) * CL_; t0 += UN) {
    float kk[UN], vv[UN], rrv[UN];
    size_t base = ((size_t)b * T_ + t0) * H_ + hh;
    #pragma unroll
    for (int i = 0; i < UN; i++) {
      kk[i] = (float)k[base + (size_t)i * H_];
      vv[i] = (float)v[base + (size_t)i * H_];
      rrv[i] = (float)r[base + (size_t)i * H_];
    }
    #pragma unroll
    for (int i = 0; i < UN; i++) {
      float kt = kk[i], vt = vv[i];
      float ct = cwv + kt;
      float cn = fmaxf(ct, norm);
      float ep = __expf(norm - cn), ec = __expf(ct - cn);
      float o = (ep * num + ec * vt) / (ep * den + ec);
      a[base + (size_t)i * H_] = (__bf16)(rrv[i] * o);
      float dpn = decay + norm;
      float nn = fmaxf(dpn, kt);
      float ed = __expf(dpn - nn), ek = __expf(kt - nn);
      num = ed * num + ek * vt;
      den = ed * den + ek;
      norm = nn;
    }
  }
  if (c == CH_ - 1) {
    ndn[id] = num;
    ndn[BH_ + id] = den;
    ndn[2 * BH_ + id] = norm;
  }
}

// ----------------------------------------------------------------------- host
extern "C" void kernel_launch(void* const* d_in, const int* in_sizes, int n_in,
                              void* d_out, int out_size, void* d_ws, size_t ws_size,
                              hipStream_t stream) {
  const float* h   = (const float*)d_in[0];
  const float* lnw = (const float*)d_in[1];
  const float* lnb = (const float*)d_in[2];
  const float* Wk  = (const float*)d_in[3];
  const float* Wv  = (const float*)d_in[4];
  const float* Wr  = (const float*)d_in[5];
  const float* Wo  = (const float*)d_in[6];
  const float* mk  = (const float*)d_in[7];
  const float* mv  = (const float*)d_in[8];
  const float* mr  = (const float*)d_in[9];
  const float* td  = (const float*)d_in[10];
  const float* cw  = (const float*)d_in[11];

  char* ws = (char*)d_ws;
  const size_t MB = 1048576;
  // Workspace layout (192 MB of 256):
  //   [0,32)    xk   (bf16, later reused as 'a' = r*wkv)
  //   [32,64)   xv   (bf16, later reused as 'r')
  //   [64,96)   xr   (bf16; dead after r-GEMM -> scan state (6 MB) lives here)
  //   [96,128)  kbuf (bf16)
  //   [128,160) vbuf (bf16)
  //   [160,192) W16: Wk/Wv/Wr/Wo bf16, 8 MB each (contiguous for cvt kernel)
  __bf16* xk   = (__bf16*)(ws);
  __bf16* xv   = (__bf16*)(ws + 32 * MB);
  __bf16* xr   = (__bf16*)(ws + 64 * MB);
  __bf16* kbuf = (__bf16*)(ws + 96 * MB);
  __bf16* vbuf = (__bf16*)(ws + 128 * MB);
  __bf16* W16  = (__bf16*)(ws + 160 * MB);
  __bf16* Wk16 = W16;
  __bf16* Wv16 = Wk16 + (size_t)H_ * H_;
  __bf16* Wr16 = Wv16 + (size_t)H_ * H_;
  __bf16* Wo16 = Wr16 + (size_t)H_ * H_;
  float* cs_num  = (float*)(ws + 64 * MB);
  float* cs_den  = cs_num + (size_t)CH_ * BH_;
  float* cs_norm = cs_den + (size_t)CH_ * BH_;
  float* px_num  = cs_norm + (size_t)CH_ * BH_;
  float* px_den  = px_num + (size_t)CH_ * BH_;
  float* px_norm = px_den + (size_t)CH_ * BH_;

  float* out  = (float*)d_out;
  float* xlast = out + (size_t)BT_ * H_;
  float* ndn   = xlast + (size_t)B_ * H_;

  dim3 cg((H_ * H_) / (256 * 8), 4);
  cvt_bf16_kernel<<<cg, 256, 0, stream>>>(Wk, Wv, Wr, Wo, W16);

  ln_mix_kernel<<<BT_, 256, 0, stream>>>(h, lnw, lnb, mk, mv, mr, xk, xv, xr, xlast);

  const int gemm_blocks = (BT_ / 256) * (H_ / 256);  // 32 * 8 = 256
  gemm_nt4<0><<<gemm_blocks, 512, 0, stream>>>(xk, Wk16, nullptr, kbuf, nullptr);
  gemm_nt4<0><<<gemm_blocks, 512, 0, stream>>>(xv, Wv16, nullptr, vbuf, nullptr);
  gemm_nt4<1><<<gemm_blocks, 512, 0, stream>>>(xr, Wr16, nullptr, xv /* r reuses xv */, nullptr);

  dim3 wg(BH_ / 256, CH_);
  wkv_pass1<<<wg, 256, 0, stream>>>(kbuf, vbuf, td, cs_num, cs_den, cs_norm);
  wkv_scan<<<BH_ / 256, 256, 0, stream>>>(cs_num, cs_den, cs_norm, td,
                                          px_num, px_den, px_norm);
  wkv_pass2<<<wg, 256, 0, stream>>>(kbuf, vbuf, xv, td, cw,
                                    px_num, px_den, px_norm,
                                    xk /* a reuses xk */, ndn);

  gemm_nt4<2><<<gemm_blocks, 512, 0, stream>>>(xk, Wo16, out, nullptr, h);
}